// Round 1
// 1363.342 us; speedup vs baseline: 1.3083x; 1.3083x over previous
//
#include <hip/hip_runtime.h>
#include <stdint.h>

#define S_LEN 2048
#define D_HEAD 64
#define N_B 2
#define N_H 16

typedef __attribute__((ext_vector_type(8))) short bf16x8;
typedef __attribute__((ext_vector_type(8))) short short8v;
typedef __attribute__((ext_vector_type(4))) float f32x4;

__device__ __forceinline__ short f2bf(float f) {
    union { float f; uint32_t u; } x; x.f = f;
    uint32_t u = x.u;
    u += 0x7FFFu + ((u >> 16) & 1u);   // RNE to bf16
    return (short)(u >> 16);
}

// Pack int32 mask -> 1 bit per element. One thread per element, ballot per wave.
__global__ void maskbits_kernel(const int* __restrict__ mask,
                                unsigned long long* __restrict__ bits) {
    int tid = blockIdx.x * 256 + threadIdx.x;
    unsigned long long b = __ballot(mask[tid] != 0);
    if ((threadIdx.x & 63) == 0) bits[tid >> 6] = b;
}

// fp32 -> bf16 (optionally scaled), 8 elements per thread, fully coalesced.
__global__ void cvt_bf16_kernel(const float* __restrict__ src,
                                short* __restrict__ dst, float scale) {
    size_t base = ((size_t)blockIdx.x * 256 + threadIdx.x) * 8;
    const f32x4* p = (const f32x4*)(src + base);
    f32x4 a = p[0], b = p[1];
    short8v o;
    #pragma unroll
    for (int j = 0; j < 4; ++j) { o[j] = f2bf(a[j] * scale); o[4 + j] = f2bf(b[j] * scale); }
    *(short8v*)(dst + base) = o;
}

// V [B,H,S,D] fp32 -> V^T [B,H,D,S] bf16, 64x64 tiles through LDS.
__global__ __launch_bounds__(256) void vtrans_kernel(const float* __restrict__ v,
                                                     short* __restrict__ vt) {
    __shared__ short t[64][65];
    const int blk = blockIdx.x;          // bh*32 + s-tile
    const int bh = blk >> 5, st = blk & 31;
    const int s0 = st * 64;
    {
        const int r = threadIdx.x >> 2, c = (threadIdx.x & 3) * 16;
        const float* src = v + ((size_t)bh * S_LEN + s0 + r) * D_HEAD + c;
        #pragma unroll
        for (int j = 0; j < 16; j += 4) {
            f32x4 x = *(const f32x4*)(src + j);
            #pragma unroll
            for (int i = 0; i < 4; ++i) t[r][c + j + i] = f2bf(x[i]);
        }
    }
    __syncthreads();
    {
        const int d = threadIdx.x >> 2, sOff = (threadIdx.x & 3) * 16;
        short8v o0, o1;
        #pragma unroll
        for (int j = 0; j < 8; ++j) o0[j] = t[sOff + j][d];
        #pragma unroll
        for (int j = 0; j < 8; ++j) o1[j] = t[sOff + 8 + j][d];
        short* dst = vt + ((size_t)bh * D_HEAD + d) * S_LEN + s0 + sOff;
        *(short8v*)dst = o0;
        *(short8v*)(dst + 8) = o1;
    }
}

// ===================== v2: pre-converted bf16 inputs, swapped QK^T =====================
// Per workgroup = one (b,h) x 64 q-rows; 4 waves x 16 rows.
// QK^T computed as mfma(K_frag, Q_frag) => C holds S^T: lane (col=q, quad) owns
// k = t*16 + quad*4 + r (4 contiguous k per reg quad) -> f32x4 stores of s and p,
// per-lane scalar softmax state, 2-shuffle cross-quad reduction.
__global__ __launch_bounds__(256) void attn_fused_v2(
    const short* __restrict__ qb, const short* __restrict__ kb,
    const short* __restrict__ vt, const uint32_t* __restrict__ mbits,
    float* __restrict__ out_o, float* __restrict__ out_p, float* __restrict__ out_s)
{
    __shared__ short pbuf[4][16][72];   // per-wave P tile [q=16][k=64], wave-private

    const int tile = blockIdx.x;        // 0..1023
    const int bh   = tile >> 5;         // 0..31
    const int qt   = tile & 31;
    const int b    = bh >> 4;

    const short* qp  = qb + (size_t)bh * S_LEN * D_HEAD;
    const short* kp  = kb + (size_t)bh * S_LEN * D_HEAD;
    const short* vtp = vt + (size_t)bh * D_HEAD * S_LEN;

    const int wave = threadIdx.x >> 6;
    const int lane = threadIdx.x & 63;
    const int col  = lane & 15;
    const int quad = lane >> 4;
    const int q0   = qt * 64 + wave * 16;
    const int qrow = q0 + col;          // this lane's q row

    // Q fragment (B operand of swapped mfma): lane holds Q[qrow][quad*8+j (+32)]
    const short* qr = qp + (size_t)qrow * D_HEAD + quad * 8;
    const bf16x8 aq0 = *(const bf16x8*)qr;
    const bf16x8 aq1 = *(const bf16x8*)(qr + 32);

    const uint32_t* wrow = mbits + (size_t)b * (S_LEN * (S_LEN / 32))
                                 + (size_t)qrow * (S_LEN / 32);
    float* srow = out_s + ((size_t)bh * S_LEN + qrow) * S_LEN;
    float* prow = out_p + ((size_t)bh * S_LEN + qrow) * S_LEN;

    float m_run = -__builtin_inff(), l_run = 0.f;

    // ================= pass 1: scores -> attn, online max/sum =================
    for (int kt = 0; kt < 32; ++kt) {
        const int kbase = kt * 64;
        const uint2 w = *(const uint2*)(wrow + kt * 2);
        f32x4 sc[4];
        __builtin_amdgcn_s_setprio(1);
        #pragma unroll
        for (int t = 0; t < 4; ++t) {
            const short* kr = kp + (size_t)(kbase + t * 16 + col) * D_HEAD + quad * 8;
            bf16x8 k0 = *(const bf16x8*)kr;
            bf16x8 k1 = *(const bf16x8*)(kr + 32);
            f32x4 c = {0.f, 0.f, 0.f, 0.f};
            c = __builtin_amdgcn_mfma_f32_16x16x32_bf16(k0, aq0, c, 0, 0, 0);
            c = __builtin_amdgcn_mfma_f32_16x16x32_bf16(k1, aq1, c, 0, 0, 0);
            sc[t] = c;   // sc[t][r] = S[qrow][kbase + t*16 + quad*4 + r]
        }
        __builtin_amdgcn_s_setprio(0);
        float mx = -__builtin_inff();
        #pragma unroll
        for (int t = 0; t < 4; ++t) {
            const uint32_t wt = (t < 2) ? w.x : w.y;
            const int sh = ((t & 1) << 4) + (quad << 2);
            #pragma unroll
            for (int r = 0; r < 4; ++r) {
                sc[t][r] += ((wt >> (sh + r)) & 1u) ? 0.f : -1e9f;
                mx = fmaxf(mx, sc[t][r]);
            }
            __builtin_nontemporal_store(sc[t], (f32x4*)(srow + kbase + t * 16 + quad * 4));
        }
        // combine across the 4 quads holding the same q row
        mx = fmaxf(mx, __shfl_xor(mx, 16));
        mx = fmaxf(mx, __shfl_xor(mx, 32));
        const float mnew  = fmaxf(m_run, mx);
        const float alpha = __expf(m_run - mnew);    // -inf -> 0 on first tile
        float ss = 0.f;
        #pragma unroll
        for (int t = 0; t < 4; ++t)
            #pragma unroll
            for (int r = 0; r < 4; ++r) ss += __expf(sc[t][r] - mnew);
        ss += __shfl_xor(ss, 16);
        ss += __shfl_xor(ss, 32);
        l_run = l_run * alpha + ss;
        m_run = mnew;
    }

    const float inv_l = 1.f / l_run;
    f32x4 acc[4];
    #pragma unroll
    for (int n = 0; n < 4; ++n) acc[n] = (f32x4){0.f, 0.f, 0.f, 0.f};

    // ================= pass 2: recompute -> attn_prob, O += P*V =================
    for (int kt = 0; kt < 32; ++kt) {
        const int kbase = kt * 64;
        const uint2 w = *(const uint2*)(wrow + kt * 2);
        f32x4 sc[4];
        __builtin_amdgcn_s_setprio(1);
        #pragma unroll
        for (int t = 0; t < 4; ++t) {
            const short* kr = kp + (size_t)(kbase + t * 16 + col) * D_HEAD + quad * 8;
            bf16x8 k0 = *(const bf16x8*)kr;
            bf16x8 k1 = *(const bf16x8*)(kr + 32);
            f32x4 c = {0.f, 0.f, 0.f, 0.f};
            c = __builtin_amdgcn_mfma_f32_16x16x32_bf16(k0, aq0, c, 0, 0, 0);
            c = __builtin_amdgcn_mfma_f32_16x16x32_bf16(k1, aq1, c, 0, 0, 0);
            sc[t] = c;
        }
        __builtin_amdgcn_s_setprio(0);
        #pragma unroll
        for (int t = 0; t < 4; ++t) {
            const uint32_t wt = (t < 2) ? w.x : w.y;
            const int sh = ((t & 1) << 4) + (quad << 2);
            f32x4 pv;
            #pragma unroll
            for (int r = 0; r < 4; ++r) {
                float val = sc[t][r] + (((wt >> (sh + r)) & 1u) ? 0.f : -1e9f);
                pv[r] = __expf(val - m_run) * inv_l;
            }
            __builtin_nontemporal_store(pv, (f32x4*)(prow + kbase + t * 16 + quad * 4));
            union { uint64_t u; short s[4]; } pk;
            #pragma unroll
            for (int r = 0; r < 4; ++r) pk.s[r] = f2bf(pv[r]);
            // pbuf is wave-private: no __syncthreads needed, lgkmcnt orders write->read
            *(uint64_t*)&pbuf[wave][col][t * 16 + quad * 4] = pk.u;
        }
        __builtin_amdgcn_s_setprio(1);
        #pragma unroll
        for (int c2 = 0; c2 < 2; ++c2) {
            const bf16x8 ap = *(const bf16x8*)&pbuf[wave][col][c2 * 32 + quad * 8];
            #pragma unroll
            for (int n = 0; n < 4; ++n) {
                const bf16x8 bv = *(const bf16x8*)(vtp + (size_t)(n * 16 + col) * S_LEN
                                                   + kbase + c2 * 32 + quad * 8);
                acc[n] = __builtin_amdgcn_mfma_f32_16x16x32_bf16(ap, bv, acc[n], 0, 0, 0);
            }
        }
        __builtin_amdgcn_s_setprio(0);
    }

    // epilogue: store O (C layout: row=quad*4+r -> q, col -> d chunk)
    float* orow = out_o + ((size_t)bh * S_LEN + q0) * D_HEAD;
    #pragma unroll
    for (int n = 0; n < 4; ++n)
        #pragma unroll
        for (int r = 0; r < 4; ++r)
            orow[(size_t)(quad * 4 + r) * D_HEAD + n * 16 + col] = acc[n][r];
}

// ===================== legacy fallback (workspace too small) =====================
template <int USE_BITS>
__global__ __launch_bounds__(256) void attn_fused(
    const float* __restrict__ qg, const float* __restrict__ kg,
    const float* __restrict__ vg, const int* __restrict__ mask32,
    const uint32_t* __restrict__ mbits,
    float* __restrict__ out_o, float* __restrict__ out_p,
    float* __restrict__ out_s)
{
    __shared__ short pbuf[4][16][72];

    const int tile = blockIdx.x;
    const int bh   = tile >> 5;
    const int qt   = tile & 31;
    const int b    = bh >> 4;

    const float* qp = qg + (size_t)bh * S_LEN * D_HEAD;
    const float* kp = kg + (size_t)bh * S_LEN * D_HEAD;
    const float* vp = vg + (size_t)bh * S_LEN * D_HEAD;
    const int*      mrow = mask32 + (size_t)b * S_LEN * S_LEN;
    const uint32_t* brow = mbits  + (size_t)b * (S_LEN * (S_LEN / 32));

    const int wave = threadIdx.x >> 6;
    const int lane = threadIdx.x & 63;
    const int col  = lane & 15;
    const int quad = lane >> 4;
    const int q0   = qt * 64 + wave * 16;

    bf16x8 aq[2];
    {
        const float* qr = qp + (size_t)(q0 + col) * D_HEAD + quad * 8;
        #pragma unroll
        for (int h = 0; h < 2; ++h) {
            const f32x4* p4 = (const f32x4*)(qr + h * 32);
            f32x4 x0 = p4[0], x1 = p4[1];
            #pragma unroll
            for (int j = 0; j < 4; ++j) {
                aq[h][j]     = f2bf(x0[j] * 0.125f);
                aq[h][4 + j] = f2bf(x1[j] * 0.125f);
            }
        }
    }

    float m_run[4], l_run[4];
    #pragma unroll
    for (int r = 0; r < 4; ++r) { m_run[r] = -__builtin_inff(); l_run[r] = 0.f; }

    float* srow = out_s + ((size_t)bh * S_LEN + q0) * S_LEN;
    float* prow = out_p + ((size_t)bh * S_LEN + q0) * S_LEN;

    for (int kt = 0; kt < 32; ++kt) {
        const int kbase = kt * 64;
        float sc[4][4];
        #pragma unroll
        for (int t = 0; t < 4; ++t) {
            f32x4 c = {0.f, 0.f, 0.f, 0.f};
            const float* kr = kp + (size_t)(kbase + t * 16 + col) * D_HEAD + quad * 8;
            #pragma unroll
            for (int h = 0; h < 2; ++h) {
                const f32x4* p4 = (const f32x4*)(kr + h * 32);
                f32x4 x0 = p4[0], x1 = p4[1];
                bf16x8 bk;
                #pragma unroll
                for (int j = 0; j < 4; ++j) { bk[j] = f2bf(x0[j]); bk[4 + j] = f2bf(x1[j]); }
                c = __builtin_amdgcn_mfma_f32_16x16x32_bf16(aq[h], bk, c, 0, 0, 0);
            }
            #pragma unroll
            for (int r = 0; r < 4; ++r) sc[t][r] = c[r];
        }
        #pragma unroll
        for (int r = 0; r < 4; ++r) {
            const int qr = q0 + quad * 4 + r;
            uint32_t w0 = 0, w1 = 0;
            if (USE_BITS) {
                const uint32_t* wp = brow + (size_t)qr * (S_LEN / 32) + (kbase >> 5);
                w0 = wp[0]; w1 = wp[1];
            }
            #pragma unroll
            for (int t = 0; t < 4; ++t) {
                int on;
                if (USE_BITS) {
                    uint32_t w = (t < 2) ? w0 : w1;
                    on = (w >> (((t & 1) << 4) + col)) & 1u;
                } else {
                    on = mrow[(size_t)qr * S_LEN + kbase + t * 16 + col] != 0;
                }
                float val = sc[t][r] + (on ? 0.f : -1e9f);
                sc[t][r] = val;
                srow[(size_t)(quad * 4 + r) * S_LEN + kbase + t * 16 + col] = val;
            }
        }
        #pragma unroll
        for (int r = 0; r < 4; ++r) {
            float x = fmaxf(fmaxf(sc[0][r], sc[1][r]), fmaxf(sc[2][r], sc[3][r]));
            x = fmaxf(x, __shfl_xor(x, 1));
            x = fmaxf(x, __shfl_xor(x, 2));
            x = fmaxf(x, __shfl_xor(x, 4));
            x = fmaxf(x, __shfl_xor(x, 8));
            float mnew  = fmaxf(m_run[r], x);
            float alpha = __expf(m_run[r] - mnew);
            float ss = __expf(sc[0][r] - mnew) + __expf(sc[1][r] - mnew)
                     + __expf(sc[2][r] - mnew) + __expf(sc[3][r] - mnew);
            ss += __shfl_xor(ss, 1);
            ss += __shfl_xor(ss, 2);
            ss += __shfl_xor(ss, 4);
            ss += __shfl_xor(ss, 8);
            l_run[r] = l_run[r] * alpha + ss;
            m_run[r] = mnew;
        }
    }

    float inv_l[4];
    #pragma unroll
    for (int r = 0; r < 4; ++r) inv_l[r] = 1.f / l_run[r];

    f32x4 acc[4];
    #pragma unroll
    for (int n = 0; n < 4; ++n) acc[n] = (f32x4){0.f, 0.f, 0.f, 0.f};

    for (int kt = 0; kt < 32; ++kt) {
        const int kbase = kt * 64;
        float pv[4][4];
        #pragma unroll
        for (int t = 0; t < 4; ++t) {
            f32x4 c = {0.f, 0.f, 0.f, 0.f};
            const float* kr = kp + (size_t)(kbase + t * 16 + col) * D_HEAD + quad * 8;
            #pragma unroll
            for (int h = 0; h < 2; ++h) {
                const f32x4* p4 = (const f32x4*)(kr + h * 32);
                f32x4 x0 = p4[0], x1 = p4[1];
                bf16x8 bk;
                #pragma unroll
                for (int j = 0; j < 4; ++j) { bk[j] = f2bf(x0[j]); bk[4 + j] = f2bf(x1[j]); }
                c = __builtin_amdgcn_mfma_f32_16x16x32_bf16(aq[h], bk, c, 0, 0, 0);
            }
            #pragma unroll
            for (int r = 0; r < 4; ++r) pv[t][r] = c[r];
        }
        #pragma unroll
        for (int r = 0; r < 4; ++r) {
            const int qr = q0 + quad * 4 + r;
            uint32_t w0 = 0, w1 = 0;
            if (USE_BITS) {
                const uint32_t* wp = brow + (size_t)qr * (S_LEN / 32) + (kbase >> 5);
                w0 = wp[0]; w1 = wp[1];
            }
            #pragma unroll
            for (int t = 0; t < 4; ++t) {
                int on;
                if (USE_BITS) {
                    uint32_t w = (t < 2) ? w0 : w1;
                    on = (w >> (((t & 1) << 4) + col)) & 1u;
                } else {
                    on = mrow[(size_t)qr * S_LEN + kbase + t * 16 + col] != 0;
                }
                float s = pv[t][r] + (on ? 0.f : -1e9f);
                float p = __expf(s - m_run[r]) * inv_l[r];
                prow[(size_t)(quad * 4 + r) * S_LEN + kbase + t * 16 + col] = p;
                pv[t][r] = p;
            }
        }
        __syncthreads();
        #pragma unroll
        for (int t = 0; t < 4; ++t)
            #pragma unroll
            for (int r = 0; r < 4; ++r)
                pbuf[wave][quad * 4 + r][t * 16 + col] = f2bf(pv[t][r]);
        __syncthreads();
        #pragma unroll
        for (int c2 = 0; c2 < 2; ++c2) {
            bf16x8 ap = *(const bf16x8*)&pbuf[wave][col][c2 * 32 + quad * 8];
            #pragma unroll
            for (int n = 0; n < 4; ++n) {
                bf16x8 bv;
                const float* vcol = vp + (size_t)(kbase + c2 * 32 + quad * 8) * D_HEAD + n * 16 + col;
                #pragma unroll
                for (int j = 0; j < 8; ++j) bv[j] = f2bf(vcol[(size_t)j * D_HEAD]);
                acc[n] = __builtin_amdgcn_mfma_f32_16x16x32_bf16(ap, bv, acc[n], 0, 0, 0);
            }
        }
    }

    float* orow = out_o + ((size_t)bh * S_LEN + q0) * D_HEAD;
    #pragma unroll
    for (int n = 0; n < 4; ++n)
        #pragma unroll
        for (int r = 0; r < 4; ++r)
            orow[(size_t)(quad * 4 + r) * D_HEAD + n * 16 + col] = acc[n][r];
}

extern "C" void kernel_launch(void* const* d_in, const int* in_sizes, int n_in,
                              void* d_out, int out_size, void* d_ws, size_t ws_size,
                              hipStream_t stream) {
    const float* q    = (const float*)d_in[0];
    const float* k    = (const float*)d_in[1];
    const float* v    = (const float*)d_in[2];
    const int*   mask = (const int*)d_in[3];

    float* out_o = (float*)d_out;                                   // [B,H,S,D]
    float* out_p = out_o + (size_t)N_B * N_H * S_LEN * D_HEAD;      // [B,H,S,S]
    float* out_s = out_p + (size_t)N_B * N_H * (size_t)S_LEN * S_LEN;

    const size_t bits_bytes = (size_t)N_B * S_LEN * (S_LEN / 8);    // 1 MiB
    const size_t elems    = (size_t)N_B * N_H * S_LEN * D_HEAD;     // 4,194,304
    const size_t bf_bytes = elems * sizeof(short);                  // 8 MiB each
    const int nblocks = N_B * N_H * (S_LEN / 64);                   // 1024

    if (ws_size >= bits_bytes + 3 * bf_bytes) {
        unsigned long long* bits = (unsigned long long*)d_ws;
        short* qb  = (short*)((char*)d_ws + bits_bytes);
        short* kb  = qb + elems;
        short* vtb = kb + elems;
        maskbits_kernel<<<(N_B * S_LEN * S_LEN) / 256, 256, 0, stream>>>(mask, bits);
        cvt_bf16_kernel<<<(int)(elems / (256 * 8)), 256, 0, stream>>>(q, qb, 0.125f);
        cvt_bf16_kernel<<<(int)(elems / (256 * 8)), 256, 0, stream>>>(k, kb, 1.0f);
        vtrans_kernel<<<N_B * N_H * (S_LEN / 64), 256, 0, stream>>>(v, vtb);
        attn_fused_v2<<<nblocks, 256, 0, stream>>>(qb, kb, vtb, (const uint32_t*)d_ws,
                                                   out_o, out_p, out_s);
    } else if (ws_size >= bits_bytes) {
        maskbits_kernel<<<(N_B * S_LEN * S_LEN) / 256, 256, 0, stream>>>(
            mask, (unsigned long long*)d_ws);
        attn_fused<1><<<nblocks, 256, 0, stream>>>(
            q, k, v, mask, (const uint32_t*)d_ws, out_o, out_p, out_s);
    } else {
        attn_fused<0><<<nblocks, 256, 0, stream>>>(
            q, k, v, mask, (const uint32_t*)nullptr, out_o, out_p, out_s);
    }
}